// Round 3
// baseline (148.911 us; speedup 1.0000x reference)
//
#include <hip/hip_runtime.h>

#define NEG 5
#define MM 6            // morphemes per word
#define NCTX 6          // 1 + NEG
#define NC (NCTX * MM)  // 36 ctx morphemes per row
#define DD 128
#define WPB 4           // waves per block (1 row per wave)
#define DROW 12         // data row stride = 2 + 2*NEG

__global__ __launch_bounds__(256) void sg_loss_kernel(
    const int*   __restrict__ data,           // [B, 12]
    const int*   __restrict__ w2m,            // [B, 6]
    const float* __restrict__ w2m_mask,       // [B, 6]
    const int*   __restrict__ c2m,            // [B, 36]
    const float* __restrict__ c2m_mask,       // [B, 36]
    const float* __restrict__ emb0,           // [V, 128]
    const float* __restrict__ emb1,           // [V, 128]
    float*       __restrict__ out,
    int B)
{
    const int lane = threadIdx.x & 63;
    // force wave-uniformity so index/mask reads become scalar loads
    const int wid  = __builtin_amdgcn_readfirstlane(threadIdx.x >> 6);
    const int b    = blockIdx.x * WPB + wid;   // wave-uniform row id

    float loss = 0.0f;

    if (b < B) {
        const int d0 = lane * 2;   // this lane's 2 dims of 128

        // ---------- scalar (wave-uniform) index/mask loads ----------
        int   wi[MM];  float wm[MM];
        #pragma unroll
        for (int m = 0; m < MM; ++m) {
            wi[m] = w2m[(size_t)b * MM + m];
            wm[m] = w2m_mask[(size_t)b * MM + m];
        }
        int   ci[NC];  float cm[NC];
        #pragma unroll
        for (int t = 0; t < NC; ++t) {
            ci[t] = c2m[(size_t)b * NC + t];
            cm[t] = c2m_mask[(size_t)b * NC + t];
        }
        float nmf[NEG];
        #pragma unroll
        for (int n = 0; n < NEG; ++n)
            nmf[n] = (float)data[(size_t)b * DROW + 2 + NEG + n];

        // ---------- issue ALL 42 row gathers before consuming any ----------
        float2 wr[MM];
        #pragma unroll
        for (int m = 0; m < MM; ++m)
            wr[m] = *reinterpret_cast<const float2*>(emb0 + (size_t)wi[m] * DD + d0);

        float2 cr[NC];
        #pragma unroll
        for (int t = 0; t < NC; ++t)
            cr[t] = *reinterpret_cast<const float2*>(emb1 + (size_t)ci[t] * DD + d0);

        // ---------- consume in issue order ----------
        float wx = 0.0f, wy = 0.0f;
        #pragma unroll
        for (int m = 0; m < MM; ++m) {
            wx += wr[m].x * wm[m];
            wy += wr[m].y * wm[m];
        }

        float p[NCTX];
        #pragma unroll
        for (int j = 0; j < NCTX; ++j) {
            float ex = 0.0f, ey = 0.0f;
            #pragma unroll
            for (int m = 0; m < MM; ++m) {
                const int t = j * MM + m;
                ex += cr[t].x * cm[t];
                ey += cr[t].y * cm[t];
            }
            p[j] = wx * ex + wy * ey;
        }

        // ---------- wave-wide butterfly reduce of the 6 dots ----------
        #pragma unroll
        for (int j = 0; j < NCTX; ++j) {
            float v = p[j];
            #pragma unroll
            for (int off = 32; off >= 1; off >>= 1)
                v += __shfl_xor(v, off, 64);
            p[j] = v;
        }

        if (lane == 0) {
            float x = fminf(fmaxf(p[0], -10.0f), 10.0f);
            loss = log1pf(expf(-x));
            #pragma unroll
            for (int n = 0; n < NEG; ++n) {
                float y = fminf(fmaxf(-p[1 + n], -10.0f), 10.0f);
                loss += log1pf(expf(-y)) * nmf[n];
            }
        }
    }

    // ---------- block reduce: 4 wave partials -> 1 atomic ----------
    __shared__ float sacc[WPB];
    if (lane == 0) sacc[wid] = loss;
    __syncthreads();
    if (threadIdx.x == 0) {
        float s = 0.0f;
        #pragma unroll
        for (int w = 0; w < WPB; ++w) s += sacc[w];
        atomicAdd(out, s);
    }
}

extern "C" void kernel_launch(void* const* d_in, const int* in_sizes, int n_in,
                              void* d_out, int out_size, void* d_ws, size_t ws_size,
                              hipStream_t stream) {
    const int*   data     = (const int*)  d_in[0];
    const int*   w2m      = (const int*)  d_in[1];
    const float* w2m_mask = (const float*)d_in[2];
    const int*   c2m      = (const int*)  d_in[3];
    const float* c2m_mask = (const float*)d_in[4];
    const float* emb0     = (const float*)d_in[5];
    const float* emb1     = (const float*)d_in[6];
    float* out = (float*)d_out;

    const int B = in_sizes[1] / MM;   // word2morph has B*6 elements

    hipMemsetAsync(out, 0, sizeof(float), stream);

    const int blocks = (B + WPB - 1) / WPB;
    sg_loss_kernel<<<blocks, 64 * WPB, 0, stream>>>(
        data, w2m, w2m_mask, c2m, c2m_mask, emb0, emb1, out, B);
}